// Round 7
// baseline (4989.713 us; speedup 1.0000x reference)
//
#include <hip/hip_runtime.h>
#include <math.h>

// ---------------------------------------------------------------------------
// VQSign r7: fix r6's conv1k scratch-spill regression — the 3-round task loop
// is now FULLY UNROLLED so pmx[rr]/pmn[rr] indices are compile-time constants
// (r6's `#pragma unroll 1` + runtime-indexed arrays spilled 48 floats/thread
// to scratch -> 2.0 GB HBM traffic). Rest identical to r6.
// ---------------------------------------------------------------------------

typedef __attribute__((ext_vector_type(8))) short short8;
typedef __attribute__((ext_vector_type(4))) float f32x4;

__device__ inline unsigned short f2bf(float x) {
    unsigned int u = __float_as_uint(x);
    u += 0x7FFFu + ((u >> 16) & 1u);          // RNE
    return (unsigned short)(u >> 16);
}
__device__ inline float bf2f(unsigned short h) {
    return __uint_as_float(((unsigned int)h) << 16);
}

// ---------------- conv1: fp32, LDS tile, pooled max/min chan-last out -------
// x [4][3][64][96][96]; pmax/pmin [4][16t][48][48][32c]; stats fused.
// block = (n,t,32x24 out tile); 768 tasks = 3/thread (fully unrolled).
__launch_bounds__(256, 3)
__global__ void conv1k(const float* __restrict__ x, const float* __restrict__ wgt,
                       const float* __restrict__ bias, float* __restrict__ pmax,
                       float* __restrict__ pmin, float* __restrict__ stats, int t0) {
    int bb = blockIdx.x;
    int xt = bb % 3; int yt = (bb / 3) % 4; int t = (bb / 12) % 16; int n = bb / 192;
    int x0 = xt * 32, y0 = yt * 24;
    __shared__ float tile[9 * 936];           // reused as 12*16*33 staging later
    __shared__ float wl[2592];
    __shared__ float sst[64];
    int tid = threadIdx.x;
    for (int i = tid; i < 2592; i += 256) wl[i] = wgt[i];
    if (tid < 64) sst[tid] = 0.f;
    for (int i = tid; i < 7956; i += 256) {
        int p = i / 884; int rem = i % 884;
        int r = rem / 34, cl = rem % 34;
        int ci = p / 3, kt = p % 3;
        int lt = t + kt - 1;
        int yy = y0 + r - 1, xx = x0 + cl - 1;
        float v = 0.f;
        if (lt >= 0 && lt <= 15 && yy >= 0 && yy < 96 && xx >= 0 && xx < 96)
            v = x[((size_t)(n * 3 + ci) * 64 + (t0 + lt)) * 9216 + yy * 96 + xx];
        tile[p * 936 + r * 36 + cl] = v;
    }
    __syncthreads();

    float pmx[3][8], pmn[3][8];               // [round][ch*4 + py*2 + px] — static idx only

    #pragma unroll
    for (int rr = 0; rr < 3; ++rr) {
        int task = tid + rr * 256;
        int tx = task & 7; int ty = (task >> 3) % 6; int cg = task / 48;
        int co0 = cg * 2;
        float bv0 = bias[co0], bv1 = bias[co0 + 1];
        float a0[4][4], a1[4][4];
        #pragma unroll
        for (int i = 0; i < 4; ++i)
            #pragma unroll
            for (int j = 0; j < 4; ++j) { a0[i][j] = bv0; a1[i][j] = bv1; }

        #pragma unroll 1
        for (int ci = 0; ci < 3; ++ci) {
            #pragma unroll
            for (int kt = 0; kt < 3; ++kt) {
                const float* wp = wl + co0 * 81 + ci * 27 + kt * 9;
                float wa[9], wb[9];
                #pragma unroll
                for (int i = 0; i < 9; ++i) { wa[i] = wp[i]; wb[i] = wp[81 + i]; }
                const float* ip = tile + (ci * 3 + kt) * 936 + (ty * 4) * 36 + tx * 4;
                #pragma unroll
                for (int j = 0; j < 6; ++j) {
                    float4 u = *(const float4*)(ip + j * 36);
                    float4 v = *(const float4*)(ip + j * 36 + 4);
                    #pragma unroll
                    for (int ky = 0; ky < 3; ++ky) {
                        int i = j - ky;
                        if (i >= 0 && i < 4) {
                            float w0 = wa[ky * 3], w1 = wa[ky * 3 + 1], w2 = wa[ky * 3 + 2];
                            a0[i][0] += w0 * u.x + w1 * u.y + w2 * u.z;
                            a0[i][1] += w0 * u.y + w1 * u.z + w2 * u.w;
                            a0[i][2] += w0 * u.z + w1 * u.w + w2 * v.x;
                            a0[i][3] += w0 * u.w + w1 * v.x + w2 * v.y;
                            float z0 = wb[ky * 3], z1 = wb[ky * 3 + 1], z2 = wb[ky * 3 + 2];
                            a1[i][0] += z0 * u.x + z1 * u.y + z2 * u.z;
                            a1[i][1] += z0 * u.y + z1 * u.z + z2 * u.w;
                            a1[i][2] += z0 * u.z + z1 * u.w + z2 * v.x;
                            a1[i][3] += z0 * u.w + z1 * v.x + z2 * v.y;
                        }
                    }
                }
            }
        }
        // stats (full-res, pre-pool) + in-register 2x2 max/min pooling
        float ls0 = 0.f, lq0 = 0.f, ls1 = 0.f, lq1 = 0.f;
        #pragma unroll
        for (int i = 0; i < 4; ++i)
            #pragma unroll
            for (int j = 0; j < 4; ++j) {
                ls0 += a0[i][j]; lq0 += a0[i][j] * a0[i][j];
                ls1 += a1[i][j]; lq1 += a1[i][j] * a1[i][j];
            }
        atomicAdd(&sst[co0 * 2], ls0);
        atomicAdd(&sst[co0 * 2 + 1], lq0);
        atomicAdd(&sst[co0 * 2 + 2], ls1);
        atomicAdd(&sst[co0 * 2 + 3], lq1);
        #pragma unroll
        for (int py = 0; py < 2; ++py)
            #pragma unroll
            for (int px = 0; px < 2; ++px) {
                float m0 = fmaxf(fmaxf(a0[2 * py][2 * px], a0[2 * py][2 * px + 1]),
                                 fmaxf(a0[2 * py + 1][2 * px], a0[2 * py + 1][2 * px + 1]));
                float n0 = fminf(fminf(a0[2 * py][2 * px], a0[2 * py][2 * px + 1]),
                                 fminf(a0[2 * py + 1][2 * px], a0[2 * py + 1][2 * px + 1]));
                float m1 = fmaxf(fmaxf(a1[2 * py][2 * px], a1[2 * py][2 * px + 1]),
                                 fmaxf(a1[2 * py + 1][2 * px], a1[2 * py + 1][2 * px + 1]));
                float n1 = fminf(fminf(a1[2 * py][2 * px], a1[2 * py][2 * px + 1]),
                                 fminf(a1[2 * py + 1][2 * px], a1[2 * py + 1][2 * px + 1]));
                pmx[rr][0 * 4 + py * 2 + px] = m0; pmn[rr][0 * 4 + py * 2 + px] = n0;
                pmx[rr][1 * 4 + py * 2 + px] = m1; pmn[rr][1 * 4 + py * 2 + px] = n1;
            }
    }
    // ---- stage + write pooled (chan-last [12yo][16xo][32c], pad 33) ----
    float* stage = tile;                      // tile reads are done
    size_t gbase = ((size_t)(n * 16 + t) * 48 + yt * 12) * (48 * 32) + (size_t)xt * 16 * 32;
    #pragma unroll
    for (int ph = 0; ph < 2; ++ph) {
        __syncthreads();
        #pragma unroll
        for (int rr = 0; rr < 3; ++rr) {
            int task = tid + rr * 256;
            int tx = task & 7; int ty = (task >> 3) % 6; int cg = task / 48;
            #pragma unroll
            for (int ch = 0; ch < 2; ++ch)
                #pragma unroll
                for (int py = 0; py < 2; ++py)
                    #pragma unroll
                    for (int px = 0; px < 2; ++px) {
                        float v = ph ? pmn[rr][ch * 4 + py * 2 + px] : pmx[rr][ch * 4 + py * 2 + px];
                        stage[((ty * 2 + py) * 16 + tx * 2 + px) * 33 + cg * 2 + ch] = v;
                    }
        }
        __syncthreads();
        float* gdst = ph ? pmin : pmax;
        #pragma unroll
        for (int k = 0; k < 6; ++k) {
            int f4 = (tid + k * 256) * 4;
            int c0 = f4 & 31; int sp = f4 >> 5;
            int xo = sp & 15; int yo = sp >> 4;
            float4 v = make_float4(stage[sp * 33 + c0], stage[sp * 33 + c0 + 1],
                                   stage[sp * 33 + c0 + 2], stage[sp * 33 + c0 + 3]);
            *(float4*)(gdst + gbase + ((size_t)yo * 48 + xo) * 32 + c0) = v;
        }
    }
    __syncthreads();
    if (tid < 64) atomicAdd(&stats[tid], sst[tid]);
}

// -------- bnpool1b: pooled max/min -> BN affine + ReLU -> P2 hi/lo ----------
__global__ void bnpool1b(const float* __restrict__ pmax, const float* __restrict__ pmin,
                         const float* __restrict__ st, const float* __restrict__ gam,
                         const float* __restrict__ bet,
                         unsigned short* __restrict__ phi, unsigned short* __restrict__ plo) {
    int i = blockIdx.x * 256 + threadIdx.x;    // 589824 = 4*16*48*48*4
    int c8 = i & 3; int xo = (i >> 2) % 48; int yo = (i / 192) % 48;
    int t = (i / 9216) % 16; int n = i / 147456;
    size_t base = (((size_t)(n * 16 + t) * 48 + yo) * 48 + xo) * 32 + c8 * 8;
    union { unsigned short s[8]; uint4 v; } Uh, Ul;
    #pragma unroll
    for (int j = 0; j < 8; ++j) {
        int ch = c8 * 8 + j;
        float mean = st[ch * 2] * (1.f / 589824.f);
        float var  = st[ch * 2 + 1] * (1.f / 589824.f) - mean * mean;
        var = var < 0.f ? 0.f : var;
        float sc = gam[ch] / sqrtf(var + 1e-5f);
        float sh = bet[ch] - mean * sc;
        float pv = sc >= 0.f ? pmax[base + j] : pmin[base + j];
        float v = fmaxf(sc * pv + sh, 0.f);
        Uh.s[j] = f2bf(v);
        Ul.s[j] = f2bf(v - bf2f(Uh.s[j]));
    }
    size_t off = ((((size_t)n * 18 + t + 1) * 50 + yo + 1) * 52 + (xo + 1)) * 32 + c8 * 8;
    *(uint4*)(phi + off) = Uh.v;
    *(uint4*)(plo + off) = Ul.v;
}

// -------- conv2: split-bf16 MFMA + fused BN stats ---------------------------
__launch_bounds__(256, 2)
__global__ void conv2k(const unsigned short* __restrict__ phi, const unsigned short* __restrict__ plo,
                       const unsigned short* __restrict__ w2p, const float* __restrict__ bias,
                       float* __restrict__ out, float* __restrict__ st) {
    __shared__ unsigned short lds[36864];
    __shared__ float sred[4][64], qred[4][64];
    int b = blockIdx.x;                        // 768
    int y0 = (b % 12) * 4; int t = (b / 12) % 16; int n = b / 192;
    int wv = threadIdx.x >> 6, lane = threadIdx.x & 63;
    int c = lane & 15, q = lane >> 4;
    int y = y0 + wv;

    f32x4 acc[4][3];
    #pragma unroll
    for (int i = 0; i < 4; ++i)
        #pragma unroll
        for (int j = 0; j < 3; ++j) acc[i][j] = (f32x4)0.f;

    const int laneoff = c * 32 + q * 8;
    for (int kt = 0; kt < 3; ++kt) {
        const uint4* src = (const uint4*)(w2p + kt * 36864);
        uint4* dst = (uint4*)lds;
        __syncthreads();
        for (int i = threadIdx.x; i < 4608; i += 256) dst[i] = src[i];
        __syncthreads();
        const unsigned short* ph_t = phi + ((size_t)(n * 18 + t + kt) * 50) * (52 * 32);
        const unsigned short* pl_t = plo + ((size_t)(n * 18 + t + kt) * 50) * (52 * 32);
        #pragma unroll
        for (int ky = 0; ky < 3; ++ky) {
            const unsigned short* rowh = ph_t + (y + ky) * (52 * 32) + laneoff;
            const unsigned short* rowl = pl_t + (y + ky) * (52 * 32) + laneoff;
            #pragma unroll
            for (int kx = 0; kx < 3; ++kx) {
                int o = ky * 3 + kx;
                const unsigned short* wb = lds + o * 4096 + laneoff;
                short8 ah[4], al[4], bh[3], bl[3];
                #pragma unroll
                for (int mb = 0; mb < 4; ++mb) {
                    ah[mb] = *(const short8*)(wb + mb * 512);
                    al[mb] = *(const short8*)(wb + 2048 + mb * 512);
                }
                #pragma unroll
                for (int xt = 0; xt < 3; ++xt) {
                    bh[xt] = *(const short8*)(rowh + (xt * 16 + kx) * 32);
                    bl[xt] = *(const short8*)(rowl + (xt * 16 + kx) * 32);
                }
                #pragma unroll
                for (int mb = 0; mb < 4; ++mb)
                    #pragma unroll
                    for (int xt = 0; xt < 3; ++xt) {
                        acc[mb][xt] = __builtin_amdgcn_mfma_f32_16x16x32_bf16(ah[mb], bh[xt], acc[mb][xt], 0, 0, 0);
                        acc[mb][xt] = __builtin_amdgcn_mfma_f32_16x16x32_bf16(ah[mb], bl[xt], acc[mb][xt], 0, 0, 0);
                        acc[mb][xt] = __builtin_amdgcn_mfma_f32_16x16x32_bf16(al[mb], bh[xt], acc[mb][xt], 0, 0, 0);
                    }
            }
        }
    }
    float* ob = out + (((size_t)(n * 16 + t) * 48) + y) * (48 * 64);
    #pragma unroll
    for (int mb = 0; mb < 4; ++mb) {
        f32x4 bv = *(const f32x4*)(bias + mb * 16 + q * 4);
        f32x4 v0 = acc[mb][0] + bv, v1 = acc[mb][1] + bv, v2 = acc[mb][2] + bv;
        *(f32x4*)(ob + (0 * 16 + c) * 64 + mb * 16 + q * 4) = v0;
        *(f32x4*)(ob + (1 * 16 + c) * 64 + mb * 16 + q * 4) = v1;
        *(f32x4*)(ob + (2 * 16 + c) * 64 + mb * 16 + q * 4) = v2;
        #pragma unroll
        for (int r = 0; r < 4; ++r) {
            float s  = v0[r] + v1[r] + v2[r];
            float q2 = v0[r] * v0[r] + v1[r] * v1[r] + v2[r] * v2[r];
            #pragma unroll
            for (int m = 1; m < 16; m <<= 1) { s += __shfl_xor(s, m, 64); q2 += __shfl_xor(q2, m, 64); }
            if (c == 0) { sred[wv][mb * 16 + q * 4 + r] = s; qred[wv][mb * 16 + q * 4 + r] = q2; }
        }
    }
    __syncthreads();
    if (threadIdx.x < 64) {
        float s = sred[0][threadIdx.x] + sred[1][threadIdx.x] + sred[2][threadIdx.x] + sred[3][threadIdx.x];
        float q2 = qred[0][threadIdx.x] + qred[1][threadIdx.x] + qred[2][threadIdx.x] + qred[3][threadIdx.x];
        atomicAdd(&st[threadIdx.x * 2], s);
        atomicAdd(&st[threadIdx.x * 2 + 1], q2);
    }
}

// -------- bnpool2: conv2 out chan-last -> P3 [n][18][26][34][64] hi/lo ------
__global__ void bnpool2k(const float* __restrict__ cin, const float* __restrict__ st,
                         const float* __restrict__ gam, const float* __restrict__ bet,
                         unsigned short* __restrict__ phi, unsigned short* __restrict__ plo) {
    int i = blockIdx.x * 256 + threadIdx.x;    // 509184
    if (i >= 509184) return;
    int oc = i & 7; int xp = (i >> 3) % 34; int yp = (i / 272) % 26;
    int tp = (i / 7072) % 18; int n = i / 127296;
    union { unsigned short s[8]; uint4 v; } Uh, Ul;
    if (tp >= 1 && tp <= 16 && yp >= 1 && yp <= 24 && xp >= 1 && xp <= 24) {
        int t = tp - 1, yo = yp - 1, xo = xp - 1;
        const float* b0 = cin + ((((size_t)(n * 16 + t) * 48) + 2 * yo) * 48 + 2 * xo) * 64 + oc * 8;
        #pragma unroll
        for (int j = 0; j < 8; ++j) {
            int ch = oc * 8 + j;
            float mean = st[ch * 2] * (1.f / 147456.f);
            float var  = st[ch * 2 + 1] * (1.f / 147456.f) - mean * mean;
            var = var < 0.f ? 0.f : var;
            float sc = gam[ch] / sqrtf(var + 1e-5f);
            float sh = bet[ch] - mean * sc;
            float a  = b0[j] * sc + sh;
            float bb = b0[64 + j] * sc + sh;
            float c2 = b0[3072 + j] * sc + sh;
            float d  = b0[3136 + j] * sc + sh;
            float v = fmaxf(fmaxf(fmaxf(a, bb), fmaxf(c2, d)), 0.f);
            Uh.s[j] = f2bf(v);
            Ul.s[j] = f2bf(v - bf2f(Uh.s[j]));
        }
    } else {
        Uh.v = make_uint4(0, 0, 0, 0);
        Ul.v = make_uint4(0, 0, 0, 0);
    }
    size_t off = ((((size_t)n * 18 + tp) * 26 + yp) * 34 + xp) * 64 + oc * 8;
    *(uint4*)(phi + off) = Uh.v;
    *(uint4*)(plo + off) = Ul.v;
}

// -------- conv3: split-bf16 MFMA + fused BN stats ---------------------------
__launch_bounds__(256, 3)
__global__ void conv3k(const unsigned short* __restrict__ phi, const unsigned short* __restrict__ plo,
                       const unsigned short* __restrict__ w3p, const float* __restrict__ bias,
                       float* __restrict__ out, float* __restrict__ st) {
    __shared__ unsigned short lds[24576];
    __shared__ float sred[4][64], qred[4][64];
    int b = blockIdx.x;                        // 768
    int y0 = (b % 6) * 4; int t = (b / 6) % 16; int n = (b / 96) % 4; int cg = b / 384;
    int wv = threadIdx.x >> 6, lane = threadIdx.x & 63;
    int c = lane & 15, q = lane >> 4;
    int y = y0 + wv;

    f32x4 acc[4][2];
    #pragma unroll
    for (int i = 0; i < 4; ++i) { acc[i][0] = (f32x4)0.f; acc[i][1] = (f32x4)0.f; }

    const int laneoff = c * 64 + q * 8;
    const int aoff = c * 32 + q * 8;
    const unsigned short* wsrc = w3p + (size_t)cg * 221184;

    for (int kt = 0; kt < 3; ++kt) {
        const unsigned short* ph_t = phi + (size_t)(n * 18 + t + kt) * (26 * 34 * 64);
        const unsigned short* pl_t = plo + (size_t)(n * 18 + t + kt) * (26 * 34 * 64);
        for (int ky = 0; ky < 3; ++ky) {
            const uint4* src = (const uint4*)(wsrc + (kt * 3 + ky) * 24576);
            uint4* dst = (uint4*)lds;
            __syncthreads();
            for (int i = threadIdx.x; i < 3072; i += 256) dst[i] = src[i];
            __syncthreads();
            const unsigned short* rowh = ph_t + (y + ky) * (34 * 64) + laneoff;
            const unsigned short* rowl = pl_t + (y + ky) * (34 * 64) + laneoff;
            #pragma unroll
            for (int kx = 0; kx < 3; ++kx) {
                #pragma unroll
                for (int kc = 0; kc < 2; ++kc) {
                    const unsigned short* wb = lds + kx * 8192 + kc * 2048 + aoff;
                    short8 ah[4], al[4], bh[2], bl[2];
                    #pragma unroll
                    for (int mb = 0; mb < 4; ++mb) {
                        ah[mb] = *(const short8*)(wb + mb * 512);
                        al[mb] = *(const short8*)(wb + 4096 + mb * 512);
                    }
                    #pragma unroll
                    for (int xt = 0; xt < 2; ++xt) {
                        bh[xt] = *(const short8*)(rowh + (xt * 16 + kx) * 64 + kc * 32);
                        bl[xt] = *(const short8*)(rowl + (xt * 16 + kx) * 64 + kc * 32);
                    }
                    #pragma unroll
                    for (int mb = 0; mb < 4; ++mb)
                        #pragma unroll
                        for (int xt = 0; xt < 2; ++xt) {
                            acc[mb][xt] = __builtin_amdgcn_mfma_f32_16x16x32_bf16(ah[mb], bh[xt], acc[mb][xt], 0, 0, 0);
                            acc[mb][xt] = __builtin_amdgcn_mfma_f32_16x16x32_bf16(ah[mb], bl[xt], acc[mb][xt], 0, 0, 0);
                            acc[mb][xt] = __builtin_amdgcn_mfma_f32_16x16x32_bf16(al[mb], bh[xt], acc[mb][xt], 0, 0, 0);
                        }
                }
            }
        }
    }
    float* ob = out + (((size_t)(n * 16 + t) * 24) + y) * (24 * 128) + cg * 64;
    #pragma unroll
    for (int mb = 0; mb < 4; ++mb) {
        f32x4 bv = *(const f32x4*)(bias + cg * 64 + mb * 16 + q * 4);
        f32x4 v0 = acc[mb][0] + bv;
        f32x4 v1 = acc[mb][1] + bv;
        *(f32x4*)(ob + c * 128 + mb * 16 + q * 4) = v0;
        if (c < 8) *(f32x4*)(ob + (16 + c) * 128 + mb * 16 + q * 4) = v1;
        #pragma unroll
        for (int r = 0; r < 4; ++r) {
            float s  = v0[r] + (c < 8 ? v1[r] : 0.f);
            float q2 = v0[r] * v0[r] + (c < 8 ? v1[r] * v1[r] : 0.f);
            #pragma unroll
            for (int m = 1; m < 16; m <<= 1) { s += __shfl_xor(s, m, 64); q2 += __shfl_xor(q2, m, 64); }
            if (c == 0) { sred[wv][mb * 16 + q * 4 + r] = s; qred[wv][mb * 16 + q * 4 + r] = q2; }
        }
    }
    __syncthreads();
    if (threadIdx.x < 64) {
        int co = cg * 64 + threadIdx.x;
        float s = sred[0][threadIdx.x] + sred[1][threadIdx.x] + sred[2][threadIdx.x] + sred[3][threadIdx.x];
        float q2 = qred[0][threadIdx.x] + qred[1][threadIdx.x] + qred[2][threadIdx.x] + qred[3][threadIdx.x];
        atomicAdd(&st[co * 2], s);
        atomicAdd(&st[co * 2 + 1], q2);
    }
}

// -------- BN + ReLU + avgpool 6x6 (chan-last in) -> enc ---------------------
__global__ void bnavgk(const float* __restrict__ x, const float* __restrict__ st,
                       const float* __restrict__ gam, const float* __restrict__ bet,
                       float* __restrict__ enc) {
    int i = blockIdx.x * 256 + threadIdx.x;    // 131072
    int c = i & 127; int xo = (i >> 7) & 3; int yo = (i >> 9) & 3;
    int t = (i >> 11) & 15; int n = i >> 15;
    float mean = st[c * 2] * (1.f / 36864.f);
    float var  = st[c * 2 + 1] * (1.f / 36864.f) - mean * mean;
    var = var < 0.f ? 0.f : var;
    float sc = gam[c] / sqrtf(var + 1e-5f);
    float sh = bet[c] - mean * sc;
    const float* base = x + ((((size_t)(n * 16 + t) * 24) + yo * 6) * 24 + xo * 6) * 128 + c;
    float s = 0.f;
    #pragma unroll
    for (int wy = 0; wy < 6; ++wy)
        #pragma unroll
        for (int wx = 0; wx < 6; ++wx)
            s += fmaxf(base[(wy * 24 + wx) * 128] * sc + sh, 0.f);
    enc[(size_t)n * 32768 + (size_t)c * 256 + t * 16 + yo * 4 + xo] = s * (1.f / 36.f);
}

// -------- weight prepack kernels -------------------------------------------
__global__ void prep2k(const float* __restrict__ c2w, unsigned short* __restrict__ w2p) {
    int i = blockIdx.x * 256 + threadIdx.x;    // 110592
    if (i >= 110592) return;
    int ci = i & 31; int co = (i >> 5) & 63; int h = (i >> 11) & 1;
    int o = (i >> 12) % 9; int kt = i / 36864;
    int ky = o / 3, kx = o % 3;
    float w = c2w[(((size_t)(co * 32 + ci) * 3 + kt) * 3 + ky) * 3 + kx];
    unsigned short hi = f2bf(w);
    w2p[i] = h ? f2bf(w - bf2f(hi)) : hi;
}
__global__ void prep3k(const float* __restrict__ c3w, unsigned short* __restrict__ w3p) {
    int i = blockIdx.x * 256 + threadIdx.x;    // 442368
    if (i >= 442368) return;
    int cil = i & 31; int cop = (i >> 5) & 63; int kc = (i >> 11) & 1; int h = (i >> 12) & 1;
    int kx = (i >> 13) % 3; int ky = (i / 24576) % 3; int kt = (i / 73728) % 3; int cg = i / 221184;
    int ci = kc * 32 + cil; int co = cg * 64 + cop;
    float w = c3w[(((size_t)(co * 64 + ci) * 3 + kt) * 3 + ky) * 3 + kx];
    unsigned short hi = f2bf(w);
    w3p[i] = h ? f2bf(w - bf2f(hi)) : hi;
}
__global__ void prepwhhk(const float* __restrict__ whh, float* __restrict__ wt) {
    int i = blockIdx.x * 256 + threadIdx.x;    // 196608
    int g = i % 768, k = i / 768;
    wt[i] = whh[(size_t)g * 256 + k];
}

// -------- codebook transpose: cb[8192][256] -> cbT[256][8192] ---------------
__global__ void transck(const float* __restrict__ cb, float* __restrict__ cbT) {
    __shared__ float t[32][33];
    int bx = blockIdx.x & 255;
    int by = blockIdx.x >> 8;
    int ld = threadIdx.x & 31, lk = threadIdx.x >> 5;
    #pragma unroll
    for (int i = 0; i < 4; ++i) {
        int kl = lk + i * 8;
        t[kl][ld] = cb[(size_t)(bx * 32 + kl) * 256 + by * 32 + ld];
    }
    __syncthreads();
    #pragma unroll
    for (int i = 0; i < 4; ++i) {
        int dl = lk + i * 8;
        cbT[(size_t)(by * 32 + dl) * 8192 + bx * 32 + ld] = t[ld][dl];
    }
}

// -------- code norms in fp64 (ascending d, matches reference order) ---------
__global__ void cnormk(const float* __restrict__ cbT, double* __restrict__ cn2) {
    int k = blockIdx.x * 256 + threadIdx.x;    // 8192
    double s = 0.0;
    for (int d = 0; d < 256; ++d) {
        double c = (double)cbT[(size_t)d * 8192 + k];
        s += c * c;
    }
    cn2[k] = s;
}

// -------- proj init: feat = pb broadcast ------------------------------------
__global__ void projinitk(const float* __restrict__ pb, float* __restrict__ feat) {
    int i = blockIdx.x * 256 + threadIdx.x;    // 7168
    feat[i] = pb[i & 255];
}

// -------- proj (K-split x8): feat[r][d] += enc[r-chunk] . pw[d-chunk] -------
__global__ void projk(const float* __restrict__ enc, const float* __restrict__ pw,
                      float* __restrict__ feat) {
    int d = blockIdx.x & 255; int ch = blockIdx.x >> 8;    // 2048 blocks
    int k0 = ch * 4096;
    float acc[28];
    #pragma unroll
    for (int e = 0; e < 28; ++e) acc[e] = 0.f;
    const float* wrow = pw + (size_t)d * 32768 + k0;
    for (int k = threadIdx.x; k < 4096; k += 256) {
        float wv = wrow[k];
        #pragma unroll
        for (int e = 0; e < 28; ++e) acc[e] += enc[(size_t)e * 32768 + k0 + k] * wv;
    }
    __shared__ float red[4 * 28];
    #pragma unroll
    for (int e = 0; e < 28; ++e) {
        float v = acc[e];
        #pragma unroll
        for (int o = 32; o > 0; o >>= 1) v += __shfl_down(v, o, 64);
        if ((threadIdx.x & 63) == 0) red[(threadIdx.x >> 6) * 28 + e] = v;
    }
    __syncthreads();
    if (threadIdx.x < 28) {
        int e = threadIdx.x;
        int l = e >> 2, n = e & 3;
        float s = red[e] + red[28 + e] + red[56 + e] + red[84 + e];
        atomicAdd(&feat[(size_t)(n * 7 + l) * 256 + d], s);
    }
}

// -------- VQ: argmin over transposed codebook, fp64, 896 blocks -------------
__global__ void quantk(const float* __restrict__ feat, const float* __restrict__ cbT,
                       const double* __restrict__ cn2, unsigned long long* __restrict__ best) {
    int kc = blockIdx.x & 31, r = blockIdx.x >> 5;     // 896 = 32kc * 28r
    int k = kc * 256 + threadIdx.x;
    __shared__ float fs[256];
    fs[threadIdx.x] = feat[(size_t)r * 256 + threadIdx.x];
    __syncthreads();
    double dot = 0.0;
    for (int d = 0; d < 256; ++d)
        dot += (double)cbT[(size_t)d * 8192 + k] * (double)fs[d];
    float s = (float)(cn2[k] - 2.0 * dot);
    unsigned int bits = __float_as_uint(s);
    unsigned int key = (bits & 0x80000000u) ? ~bits : (bits | 0x80000000u);
    unsigned long long p = ((unsigned long long)key << 32) | (unsigned int)k;
    #pragma unroll
    for (int o = 32; o > 0; o >>= 1) {
        unsigned long long qv = __shfl_down(p, o, 64);
        if (qv < p) p = qv;
    }
    if ((threadIdx.x & 63) == 0) atomicMin(&best[r], p);
}

__global__ void gatherk(const unsigned long long* __restrict__ best,
                        const float* __restrict__ feat, const float* __restrict__ cb,
                        float* __restrict__ dout, float* __restrict__ quant,
                        float* __restrict__ acc) {
    int r = blockIdx.x;
    int d = threadIdx.x;
    int idx = (int)(best[r] & 0xFFFFFFFFull);
    float q = cb[(size_t)idx * 256 + d];
    quant[r * 256 + d] = q;
    dout[28 + r * 256 + d] = q;
    if (d == 0) dout[r] = (float)idx;
    float df = feat[r * 256 + d] - q;
    float v = df * df;
    #pragma unroll
    for (int o = 32; o > 0; o >>= 1) v += __shfl_down(v, o, 64);
    if ((d & 63) == 0) atomicAdd(&acc[0], v);
}

__global__ void gxk(const float* __restrict__ quant, const float* __restrict__ wih,
                    const float* __restrict__ bih, float* __restrict__ gx) {
    int o = blockIdx.x * 256 + threadIdx.x;
    int g = o % 768; int t = (o / 768) % 6; int n = o / (768 * 6);
    const float* q = quant + (size_t)(n * 7 + t) * 256;
    const float* w = wih + (size_t)g * 256;
    float s = bih[g];
    #pragma unroll 4
    for (int d = 0; d < 256; ++d) s += q[d] * w[d];
    gx[o] = s;
}

// -------- all 6 GRU steps in one kernel (block = batch b) -------------------
__global__ void gru_allk(const float* __restrict__ gx, const float* __restrict__ wt,
                         const float* __restrict__ bhh, const float* __restrict__ feat,
                         float* __restrict__ acc) {
    int b = blockIdx.x;        // 4
    int d = threadIdx.x;       // 256
    __shared__ float hs[256];
    hs[d] = 0.f;
    __syncthreads();
    float ctx = 0.f;
    for (int t = 0; t < 6; ++t) {
        float g0 = bhh[d], g1 = bhh[256 + d], g2 = bhh[512 + d];
        #pragma unroll 4
        for (int k = 0; k < 256; ++k) {
            float hv = hs[k];
            const float* wr = wt + (size_t)k * 768;
            g0 += wr[d] * hv; g1 += wr[256 + d] * hv; g2 += wr[512 + d] * hv;
        }
        const float* gxr = gx + (size_t)(b * 6 + t) * 768;
        float xr = gxr[d], xz = gxr[256 + d], xn = gxr[512 + d];
        float rr = 1.f / (1.f + expf(-(xr + g0)));
        float zz = 1.f / (1.f + expf(-(xz + g1)));
        float nn = tanhf(xn + rr * g2);
        float h2 = (1.f - zz) * nn + zz * hs[d];
        __syncthreads();
        hs[d] = h2;
        __syncthreads();
        float df = h2 - feat[(size_t)(b * 7 + t + 1) * 256 + d];
        ctx += df * df;
    }
    #pragma unroll
    for (int o = 32; o > 0; o >>= 1) ctx += __shfl_down(ctx, o, 64);
    if ((d & 63) == 0) atomicAdd(&acc[1], ctx);
}

__global__ void fink(const float* __restrict__ acc, float* __restrict__ dout) {
    float comm = acc[0] / 7168.f;
    float ctx  = acc[1] / 6144.f;
    dout[7196] = comm;
    dout[7197] = comm;
    dout[7198] = ctx;
    dout[7199] = comm + 0.25f * comm + 0.1f * ctx;
}

// ---------------------------------------------------------------------------
extern "C" void kernel_launch(void* const* d_in, const int* in_sizes, int n_in,
                              void* d_out, int out_size, void* d_ws, size_t ws_size,
                              hipStream_t stream) {
    (void)in_sizes; (void)n_in; (void)out_size; (void)ws_size;
    const float* x    = (const float*)d_in[0];
    const float* c1w  = (const float*)d_in[1];
    const float* c1b  = (const float*)d_in[2];
    const float* bn1g = (const float*)d_in[3];
    const float* bn1b = (const float*)d_in[4];
    const float* c2w  = (const float*)d_in[5];
    const float* c2b  = (const float*)d_in[6];
    const float* bn2g = (const float*)d_in[7];
    const float* bn2b = (const float*)d_in[8];
    const float* c3w  = (const float*)d_in[9];
    const float* c3b  = (const float*)d_in[10];
    const float* bn3g = (const float*)d_in[11];
    const float* bn3b = (const float*)d_in[12];
    const float* pw   = (const float*)d_in[13];
    const float* pb   = (const float*)d_in[14];
    const float* cb   = (const float*)d_in[15];
    const float* wih  = (const float*)d_in[16];
    const float* whh  = (const float*)d_in[17];
    const float* bih  = (const float*)d_in[18];
    const float* bhh  = (const float*)d_in[19];
    float* out = (float*)d_out;

    // ---- workspace layout (bytes) ----
    char* w = (char*)d_ws;
    float* A  = (float*)w;                         w += 75497472;   // conv2/3 outs; pmax/pmin + cbT alias
    float* PMAX = A;                                                // 18.87 MB (alias)
    float* PMIN = A + 4718592;                                      // 18.87 MB (alias)
    float* cbT = A;                                                 // 8 MB (alias, post-loop)
    double* cn2 = (double*)((char*)A + 8388608);                    // 64 KB (alias, post-loop)
    char*  SH = w;                                 w += 16293888;   // P3 hi/lo
    unsigned short* P3h = (unsigned short*)SH;
    unsigned short* P3l = (unsigned short*)(SH + 8146944);
    unsigned short* P2h = (unsigned short*)w;      w += 11980800;
    unsigned short* P2l = (unsigned short*)w;      w += 11980800;
    unsigned short* W2P = (unsigned short*)w;      w += 221184;
    unsigned short* W3P = (unsigned short*)w;      w += 884736;
    float* WT    = (float*)w;                      w += 786432;     // whh transposed [256][768]
    float* enc   = (float*)w;                      w += 3670016;
    float* feat  = (float*)w;                      w += 28672;
    float* quant = (float*)w;                      w += 28672;
    float* gx    = (float*)w;                      w += 73728;
    float* statsA = (float*)w;                     w += 21504;      // 21 x 256 floats
    float* acc    = (float*)w;                     w += 16;
    unsigned long long* best = (unsigned long long*)w;  w += 224;

    // ---- per-launch init ----
    hipMemsetAsync(P2h, 0, 11980800 * 2, stream);                  // P2 hi+lo pads
    hipMemsetAsync(statsA, 0, 21504 + 16, stream);                 // stats + acc
    hipMemsetAsync(best, 0xFF, 224, stream);
    prep2k<<<432, 256, 0, stream>>>(c2w, W2P);
    prep3k<<<1728, 256, 0, stream>>>(c3w, W3P);
    prepwhhk<<<768, 256, 0, stream>>>(whh, WT);

    for (int l = 0; l < 7; ++l) {
        float* st1 = statsA + (l * 3 + 0) * 256;
        float* st2 = statsA + (l * 3 + 1) * 256;
        float* st3 = statsA + (l * 3 + 2) * 256;
        conv1k<<<768, 256, 0, stream>>>(x, c1w, c1b, PMAX, PMIN, st1, l * 8);
        bnpool1b<<<2304, 256, 0, stream>>>(PMAX, PMIN, st1, bn1g, bn1b, P2h, P2l);
        conv2k<<<768, 256, 0, stream>>>(P2h, P2l, W2P, c2b, A, st2);
        bnpool2k<<<1989, 256, 0, stream>>>(A, st2, bn2g, bn2b, P3h, P3l);
        conv3k<<<768, 256, 0, stream>>>(P3h, P3l, W3P, c3b, A, st3);
        bnavgk<<<512, 256, 0, stream>>>(A, st3, bn3g, bn3b, enc + (size_t)l * 131072);
    }

    // A is free now: build transposed codebook + norms in its space
    transck<<<2048, 256, 0, stream>>>(cb, cbT);
    cnormk<<<32, 256, 0, stream>>>(cbT, cn2);
    projinitk<<<28, 256, 0, stream>>>(pb, feat);
    projk<<<2048, 256, 0, stream>>>(enc, pw, feat);
    quantk<<<896, 256, 0, stream>>>(feat, cbT, cn2, best);
    gatherk<<<28, 256, 0, stream>>>(best, feat, cb, out, quant, acc);
    gxk<<<72, 256, 0, stream>>>(quant, wih, bih, gx);
    gru_allk<<<4, 256, 0, stream>>>(gx, WT, bhh, feat, acc);
    fink<<<1, 1, 0, stream>>>(acc, out);
}

// Round 8
// 2404.099 us; speedup vs baseline: 2.0755x; 2.0755x over previous
//
#include <hip/hip_runtime.h>
#include <math.h>

// ---------------------------------------------------------------------------
// VQSign r8: conv1k rebuilt spill-proof. r6/r7 kept accumulator/pool arrays
// in scratch (VGPR=84, ~1.8 GB HBM scratch residue). Now: accumulators are
// named f32x4 SSA values (shufflevector column shifts), weights are named
// scalars from b128-aligned LDS, pooled max/min stored DIRECTLY to global
// (lane map cg=tid&15 -> 16 lanes cover contiguous 128 B), no carry arrays.
// ---------------------------------------------------------------------------

typedef __attribute__((ext_vector_type(8))) short short8;
typedef __attribute__((ext_vector_type(4))) float f32x4;

__device__ inline unsigned short f2bf(float x) {
    unsigned int u = __float_as_uint(x);
    u += 0x7FFFu + ((u >> 16) & 1u);          // RNE
    return (unsigned short)(u >> 16);
}
__device__ inline float bf2f(unsigned short h) {
    return __uint_as_float(((unsigned int)h) << 16);
}
__device__ inline f32x4 vmax4(f32x4 a, f32x4 b) {
    return (f32x4){fmaxf(a.x, b.x), fmaxf(a.y, b.y), fmaxf(a.z, b.z), fmaxf(a.w, b.w)};
}
__device__ inline f32x4 vmin4(f32x4 a, f32x4 b) {
    return (f32x4){fminf(a.x, b.x), fminf(a.y, b.y), fminf(a.z, b.z), fminf(a.w, b.w)};
}

// ---------------- conv1: fp32, LDS tile, pooled max/min chan-last out -------
// x [4][3][64][96][96]; pmax/pmin [4][16t][48y][48x][32c]; stats fused.
// block=(n,t,32x24 tile); lane-fixed cg=tid&15; rounds vary sp=rr*16+(tid>>4).
#define C1LOADR(J) \
    f32x4 u = *(const f32x4*)(ip + (J) * 36); \
    f32x4 w4 = *(const f32x4*)(ip + (J) * 36 + 4); \
    f32x4 sA = u; \
    f32x4 sB = __builtin_shufflevector(u, w4, 1, 2, 3, 4); \
    f32x4 sC = __builtin_shufflevector(u, w4, 2, 3, 4, 5);
#define C1UPD0(I) a0_##I += wa0 * sA + wa1 * sB + wa2 * sC; a1_##I += wb0 * sA + wb1 * sB + wb2 * sC;
#define C1UPD1(I) a0_##I += wa3 * sA + wa4 * sB + wa5 * sC; a1_##I += wb3 * sA + wb4 * sB + wb5 * sC;
#define C1UPD2(I) a0_##I += wa6 * sA + wa7 * sB + wa8 * sC; a1_##I += wb6 * sA + wb7 * sB + wb8 * sC;

__launch_bounds__(256, 3)
__global__ void conv1k(const float* __restrict__ x, const float* __restrict__ wgt,
                       const float* __restrict__ bias, float* __restrict__ pmax,
                       float* __restrict__ pmin, float* __restrict__ stats, int t0) {
    int bb = blockIdx.x;
    int xt = bb % 3; int yt = (bb / 3) % 4; int t = (bb / 12) % 16; int n = bb / 192;
    int x0 = xt * 32, y0 = yt * 24;
    __shared__ float tile[9 * 936];           // [p=ci*3+kt][26 rows][36 (34 used)]
    __shared__ float wl[3456];                // [9p][32co][12 (9 used)] - b128 aligned
    __shared__ float sst[64];
    int tid = threadIdx.x;
    for (int i = tid; i < 3456; i += 256) {
        int idx = i % 12; int r = i / 12;
        int co = r & 31; int p = r >> 5;
        wl[i] = idx < 9 ? wgt[co * 81 + p * 9 + idx] : 0.f;
    }
    if (tid < 64) sst[tid] = 0.f;
    for (int i = tid; i < 7956; i += 256) {
        int p = i / 884; int rem = i % 884;
        int r = rem / 34, cl = rem % 34;
        int ci = p / 3, kt = p % 3;
        int lt = t + kt - 1;
        int yy = y0 + r - 1, xx = x0 + cl - 1;
        float v = 0.f;
        if (lt >= 0 && lt <= 15 && yy >= 0 && yy < 96 && xx >= 0 && xx < 96)
            v = x[((size_t)(n * 3 + ci) * 64 + (t0 + lt)) * 9216 + yy * 96 + cl + x0 - 1];
        tile[p * 936 + r * 36 + cl] = v;
    }
    __syncthreads();

    int cg = tid & 15;            // lane-fixed channel pair
    int co0 = cg * 2;
    float bv0 = bias[co0], bv1 = bias[co0 + 1];
    float ls0 = 0.f, lq0 = 0.f, ls1 = 0.f, lq1 = 0.f;
    size_t nt48 = (size_t)(n * 16 + t) * 48;

    #pragma unroll 1
    for (int rr = 0; rr < 3; ++rr) {
        int sp = rr * 16 + (tid >> 4);
        int tx = sp & 7, ty = sp >> 3;
        f32x4 a0_0 = (f32x4)bv0, a0_1 = (f32x4)bv0, a0_2 = (f32x4)bv0, a0_3 = (f32x4)bv0;
        f32x4 a1_0 = (f32x4)bv1, a1_1 = (f32x4)bv1, a1_2 = (f32x4)bv1, a1_3 = (f32x4)bv1;

        #pragma unroll 1
        for (int p = 0; p < 9; ++p) {
            const float* wpk = wl + ((p * 32 + co0) * 12);
            f32x4 wv0 = *(const f32x4*)(wpk);
            f32x4 wv1 = *(const f32x4*)(wpk + 4);
            f32x4 wv2 = *(const f32x4*)(wpk + 8);
            f32x4 wv3 = *(const f32x4*)(wpk + 12);
            f32x4 wv4 = *(const f32x4*)(wpk + 16);
            f32x4 wv5 = *(const f32x4*)(wpk + 20);
            float wa0 = wv0.x, wa1 = wv0.y, wa2 = wv0.z, wa3 = wv0.w;
            float wa4 = wv1.x, wa5 = wv1.y, wa6 = wv1.z, wa7 = wv1.w;
            float wa8 = wv2.x;
            float wb0 = wv3.x, wb1 = wv3.y, wb2 = wv3.z, wb3 = wv3.w;
            float wb4 = wv4.x, wb5 = wv4.y, wb6 = wv4.z, wb7 = wv4.w;
            float wb8 = wv5.x;
            const float* ip = tile + p * 936 + (ty * 4) * 36 + tx * 4;
            { C1LOADR(0) C1UPD0(0) }
            { C1LOADR(1) C1UPD0(1) C1UPD1(0) }
            { C1LOADR(2) C1UPD0(2) C1UPD1(1) C1UPD2(0) }
            { C1LOADR(3) C1UPD0(3) C1UPD1(2) C1UPD2(1) }
            { C1LOADR(4) C1UPD1(3) C1UPD2(2) }
            { C1LOADR(5) C1UPD2(3) }
        }

        // stats (full-res, pre-pool), accumulate in registers across rounds
        f32x4 s4 = a0_0 + a0_1 + a0_2 + a0_3;
        ls0 += s4.x + s4.y + s4.z + s4.w;
        f32x4 q4 = a0_0 * a0_0 + a0_1 * a0_1 + a0_2 * a0_2 + a0_3 * a0_3;
        lq0 += q4.x + q4.y + q4.z + q4.w;
        f32x4 s5 = a1_0 + a1_1 + a1_2 + a1_3;
        ls1 += s5.x + s5.y + s5.z + s5.w;
        f32x4 q5 = a1_0 * a1_0 + a1_1 * a1_1 + a1_2 * a1_2 + a1_3 * a1_3;
        lq1 += q5.x + q5.y + q5.z + q5.w;

        // 2x2 max/min pool in-register, direct coalesced stores
        f32x4 mx0a = vmax4(a0_0, a0_1), mx0b = vmax4(a0_2, a0_3);
        f32x4 mn0a = vmin4(a0_0, a0_1), mn0b = vmin4(a0_2, a0_3);
        f32x4 mx1a = vmax4(a1_0, a1_1), mx1b = vmax4(a1_2, a1_3);
        f32x4 mn1a = vmin4(a1_0, a1_1), mn1b = vmin4(a1_2, a1_3);
        size_t row0 = (nt48 + (size_t)(yt * 12 + ty * 2)) * 1536 + (size_t)(xt * 16 + tx * 2) * 32 + co0;
        size_t row1 = row0 + 1536;
        *(float2*)(pmax + row0)      = make_float2(fmaxf(mx0a.x, mx0a.y), fmaxf(mx1a.x, mx1a.y));
        *(float2*)(pmax + row0 + 32) = make_float2(fmaxf(mx0a.z, mx0a.w), fmaxf(mx1a.z, mx1a.w));
        *(float2*)(pmax + row1)      = make_float2(fmaxf(mx0b.x, mx0b.y), fmaxf(mx1b.x, mx1b.y));
        *(float2*)(pmax + row1 + 32) = make_float2(fmaxf(mx0b.z, mx0b.w), fmaxf(mx1b.z, mx1b.w));
        *(float2*)(pmin + row0)      = make_float2(fminf(mn0a.x, mn0a.y), fminf(mn1a.x, mn1a.y));
        *(float2*)(pmin + row0 + 32) = make_float2(fminf(mn0a.z, mn0a.w), fminf(mn1a.z, mn1a.w));
        *(float2*)(pmin + row1)      = make_float2(fminf(mn0b.x, mn0b.y), fminf(mn1b.x, mn1b.y));
        *(float2*)(pmin + row1 + 32) = make_float2(fminf(mn0b.z, mn0b.w), fminf(mn1b.z, mn1b.w));
    }

    // stats: reduce lanes sharing cg (stride 16/32 within wave), then LDS+global
    ls0 += __shfl_xor(ls0, 16, 64); ls0 += __shfl_xor(ls0, 32, 64);
    lq0 += __shfl_xor(lq0, 16, 64); lq0 += __shfl_xor(lq0, 32, 64);
    ls1 += __shfl_xor(ls1, 16, 64); ls1 += __shfl_xor(ls1, 32, 64);
    lq1 += __shfl_xor(lq1, 16, 64); lq1 += __shfl_xor(lq1, 32, 64);
    if ((tid & 63) < 16) {
        atomicAdd(&sst[co0 * 2], ls0);
        atomicAdd(&sst[co0 * 2 + 1], lq0);
        atomicAdd(&sst[co0 * 2 + 2], ls1);
        atomicAdd(&sst[co0 * 2 + 3], lq1);
    }
    __syncthreads();
    if (tid < 64) atomicAdd(&stats[tid], sst[tid]);
}

// -------- bnpool1b: pooled max/min -> BN affine + ReLU -> P2 hi/lo ----------
__global__ void bnpool1b(const float* __restrict__ pmax, const float* __restrict__ pmin,
                         const float* __restrict__ st, const float* __restrict__ gam,
                         const float* __restrict__ bet,
                         unsigned short* __restrict__ phi, unsigned short* __restrict__ plo) {
    int i = blockIdx.x * 256 + threadIdx.x;    // 589824 = 4*16*48*48*4
    int c8 = i & 3; int xo = (i >> 2) % 48; int yo = (i / 192) % 48;
    int t = (i / 9216) % 16; int n = i / 147456;
    size_t base = (((size_t)(n * 16 + t) * 48 + yo) * 48 + xo) * 32 + c8 * 8;
    union { unsigned short s[8]; uint4 v; } Uh, Ul;
    #pragma unroll
    for (int j = 0; j < 8; ++j) {
        int ch = c8 * 8 + j;
        float mean = st[ch * 2] * (1.f / 589824.f);
        float var  = st[ch * 2 + 1] * (1.f / 589824.f) - mean * mean;
        var = var < 0.f ? 0.f : var;
        float sc = gam[ch] / sqrtf(var + 1e-5f);
        float sh = bet[ch] - mean * sc;
        float pv = sc >= 0.f ? pmax[base + j] : pmin[base + j];
        float v = fmaxf(sc * pv + sh, 0.f);
        Uh.s[j] = f2bf(v);
        Ul.s[j] = f2bf(v - bf2f(Uh.s[j]));
    }
    size_t off = ((((size_t)n * 18 + t + 1) * 50 + yo + 1) * 52 + (xo + 1)) * 32 + c8 * 8;
    *(uint4*)(phi + off) = Uh.v;
    *(uint4*)(plo + off) = Ul.v;
}

// -------- conv2: split-bf16 MFMA + fused BN stats ---------------------------
__launch_bounds__(256, 2)
__global__ void conv2k(const unsigned short* __restrict__ phi, const unsigned short* __restrict__ plo,
                       const unsigned short* __restrict__ w2p, const float* __restrict__ bias,
                       float* __restrict__ out, float* __restrict__ st) {
    __shared__ unsigned short lds[36864];
    __shared__ float sred[4][64], qred[4][64];
    int b = blockIdx.x;                        // 768
    int y0 = (b % 12) * 4; int t = (b / 12) % 16; int n = b / 192;
    int wv = threadIdx.x >> 6, lane = threadIdx.x & 63;
    int c = lane & 15, q = lane >> 4;
    int y = y0 + wv;

    f32x4 acc[4][3];
    #pragma unroll
    for (int i = 0; i < 4; ++i)
        #pragma unroll
        for (int j = 0; j < 3; ++j) acc[i][j] = (f32x4)0.f;

    const int laneoff = c * 32 + q * 8;
    for (int kt = 0; kt < 3; ++kt) {
        const uint4* src = (const uint4*)(w2p + kt * 36864);
        uint4* dst = (uint4*)lds;
        __syncthreads();
        for (int i = threadIdx.x; i < 4608; i += 256) dst[i] = src[i];
        __syncthreads();
        const unsigned short* ph_t = phi + ((size_t)(n * 18 + t + kt) * 50) * (52 * 32);
        const unsigned short* pl_t = plo + ((size_t)(n * 18 + t + kt) * 50) * (52 * 32);
        #pragma unroll
        for (int ky = 0; ky < 3; ++ky) {
            const unsigned short* rowh = ph_t + (y + ky) * (52 * 32) + laneoff;
            const unsigned short* rowl = pl_t + (y + ky) * (52 * 32) + laneoff;
            #pragma unroll
            for (int kx = 0; kx < 3; ++kx) {
                int o = ky * 3 + kx;
                const unsigned short* wb = lds + o * 4096 + laneoff;
                short8 ah[4], al[4], bh[3], bl[3];
                #pragma unroll
                for (int mb = 0; mb < 4; ++mb) {
                    ah[mb] = *(const short8*)(wb + mb * 512);
                    al[mb] = *(const short8*)(wb + 2048 + mb * 512);
                }
                #pragma unroll
                for (int xt = 0; xt < 3; ++xt) {
                    bh[xt] = *(const short8*)(rowh + (xt * 16 + kx) * 32);
                    bl[xt] = *(const short8*)(rowl + (xt * 16 + kx) * 32);
                }
                #pragma unroll
                for (int mb = 0; mb < 4; ++mb)
                    #pragma unroll
                    for (int xt = 0; xt < 3; ++xt) {
                        acc[mb][xt] = __builtin_amdgcn_mfma_f32_16x16x32_bf16(ah[mb], bh[xt], acc[mb][xt], 0, 0, 0);
                        acc[mb][xt] = __builtin_amdgcn_mfma_f32_16x16x32_bf16(ah[mb], bl[xt], acc[mb][xt], 0, 0, 0);
                        acc[mb][xt] = __builtin_amdgcn_mfma_f32_16x16x32_bf16(al[mb], bh[xt], acc[mb][xt], 0, 0, 0);
                    }
            }
        }
    }
    float* ob = out + (((size_t)(n * 16 + t) * 48) + y) * (48 * 64);
    #pragma unroll
    for (int mb = 0; mb < 4; ++mb) {
        f32x4 bv = *(const f32x4*)(bias + mb * 16 + q * 4);
        f32x4 v0 = acc[mb][0] + bv, v1 = acc[mb][1] + bv, v2 = acc[mb][2] + bv;
        *(f32x4*)(ob + (0 * 16 + c) * 64 + mb * 16 + q * 4) = v0;
        *(f32x4*)(ob + (1 * 16 + c) * 64 + mb * 16 + q * 4) = v1;
        *(f32x4*)(ob + (2 * 16 + c) * 64 + mb * 16 + q * 4) = v2;
        #pragma unroll
        for (int r = 0; r < 4; ++r) {
            float s  = v0[r] + v1[r] + v2[r];
            float q2 = v0[r] * v0[r] + v1[r] * v1[r] + v2[r] * v2[r];
            #pragma unroll
            for (int m = 1; m < 16; m <<= 1) { s += __shfl_xor(s, m, 64); q2 += __shfl_xor(q2, m, 64); }
            if (c == 0) { sred[wv][mb * 16 + q * 4 + r] = s; qred[wv][mb * 16 + q * 4 + r] = q2; }
        }
    }
    __syncthreads();
    if (threadIdx.x < 64) {
        float s = sred[0][threadIdx.x] + sred[1][threadIdx.x] + sred[2][threadIdx.x] + sred[3][threadIdx.x];
        float q2 = qred[0][threadIdx.x] + qred[1][threadIdx.x] + qred[2][threadIdx.x] + qred[3][threadIdx.x];
        atomicAdd(&st[threadIdx.x * 2], s);
        atomicAdd(&st[threadIdx.x * 2 + 1], q2);
    }
}

// -------- bnpool2: conv2 out chan-last -> P3 [n][18][26][34][64] hi/lo ------
__global__ void bnpool2k(const float* __restrict__ cin, const float* __restrict__ st,
                         const float* __restrict__ gam, const float* __restrict__ bet,
                         unsigned short* __restrict__ phi, unsigned short* __restrict__ plo) {
    int i = blockIdx.x * 256 + threadIdx.x;    // 509184
    if (i >= 509184) return;
    int oc = i & 7; int xp = (i >> 3) % 34; int yp = (i / 272) % 26;
    int tp = (i / 7072) % 18; int n = i / 127296;
    union { unsigned short s[8]; uint4 v; } Uh, Ul;
    if (tp >= 1 && tp <= 16 && yp >= 1 && yp <= 24 && xp >= 1 && xp <= 24) {
        int t = tp - 1, yo = yp - 1, xo = xp - 1;
        const float* b0 = cin + ((((size_t)(n * 16 + t) * 48) + 2 * yo) * 48 + 2 * xo) * 64 + oc * 8;
        #pragma unroll
        for (int j = 0; j < 8; ++j) {
            int ch = oc * 8 + j;
            float mean = st[ch * 2] * (1.f / 147456.f);
            float var  = st[ch * 2 + 1] * (1.f / 147456.f) - mean * mean;
            var = var < 0.f ? 0.f : var;
            float sc = gam[ch] / sqrtf(var + 1e-5f);
            float sh = bet[ch] - mean * sc;
            float a  = b0[j] * sc + sh;
            float bb = b0[64 + j] * sc + sh;
            float c2 = b0[3072 + j] * sc + sh;
            float d  = b0[3136 + j] * sc + sh;
            float v = fmaxf(fmaxf(fmaxf(a, bb), fmaxf(c2, d)), 0.f);
            Uh.s[j] = f2bf(v);
            Ul.s[j] = f2bf(v - bf2f(Uh.s[j]));
        }
    } else {
        Uh.v = make_uint4(0, 0, 0, 0);
        Ul.v = make_uint4(0, 0, 0, 0);
    }
    size_t off = ((((size_t)n * 18 + tp) * 26 + yp) * 34 + xp) * 64 + oc * 8;
    *(uint4*)(phi + off) = Uh.v;
    *(uint4*)(plo + off) = Ul.v;
}

// -------- conv3: split-bf16 MFMA + fused BN stats ---------------------------
__launch_bounds__(256, 3)
__global__ void conv3k(const unsigned short* __restrict__ phi, const unsigned short* __restrict__ plo,
                       const unsigned short* __restrict__ w3p, const float* __restrict__ bias,
                       float* __restrict__ out, float* __restrict__ st) {
    __shared__ unsigned short lds[24576];
    __shared__ float sred[4][64], qred[4][64];
    int b = blockIdx.x;                        // 768
    int y0 = (b % 6) * 4; int t = (b / 6) % 16; int n = (b / 96) % 4; int cg = b / 384;
    int wv = threadIdx.x >> 6, lane = threadIdx.x & 63;
    int c = lane & 15, q = lane >> 4;
    int y = y0 + wv;

    f32x4 acc[4][2];
    #pragma unroll
    for (int i = 0; i < 4; ++i) { acc[i][0] = (f32x4)0.f; acc[i][1] = (f32x4)0.f; }

    const int laneoff = c * 64 + q * 8;
    const int aoff = c * 32 + q * 8;
    const unsigned short* wsrc = w3p + (size_t)cg * 221184;

    for (int kt = 0; kt < 3; ++kt) {
        const unsigned short* ph_t = phi + (size_t)(n * 18 + t + kt) * (26 * 34 * 64);
        const unsigned short* pl_t = plo + (size_t)(n * 18 + t + kt) * (26 * 34 * 64);
        for (int ky = 0; ky < 3; ++ky) {
            const uint4* src = (const uint4*)(wsrc + (kt * 3 + ky) * 24576);
            uint4* dst = (uint4*)lds;
            __syncthreads();
            for (int i = threadIdx.x; i < 3072; i += 256) dst[i] = src[i];
            __syncthreads();
            const unsigned short* rowh = ph_t + (y + ky) * (34 * 64) + laneoff;
            const unsigned short* rowl = pl_t + (y + ky) * (34 * 64) + laneoff;
            #pragma unroll
            for (int kx = 0; kx < 3; ++kx) {
                #pragma unroll
                for (int kc = 0; kc < 2; ++kc) {
                    const unsigned short* wb = lds + kx * 8192 + kc * 2048 + aoff;
                    short8 ah[4], al[4], bh[2], bl[2];
                    #pragma unroll
                    for (int mb = 0; mb < 4; ++mb) {
                        ah[mb] = *(const short8*)(wb + mb * 512);
                        al[mb] = *(const short8*)(wb + 4096 + mb * 512);
                    }
                    #pragma unroll
                    for (int xt = 0; xt < 2; ++xt) {
                        bh[xt] = *(const short8*)(rowh + (xt * 16 + kx) * 64 + kc * 32);
                        bl[xt] = *(const short8*)(rowl + (xt * 16 + kx) * 64 + kc * 32);
                    }
                    #pragma unroll
                    for (int mb = 0; mb < 4; ++mb)
                        #pragma unroll
                        for (int xt = 0; xt < 2; ++xt) {
                            acc[mb][xt] = __builtin_amdgcn_mfma_f32_16x16x32_bf16(ah[mb], bh[xt], acc[mb][xt], 0, 0, 0);
                            acc[mb][xt] = __builtin_amdgcn_mfma_f32_16x16x32_bf16(ah[mb], bl[xt], acc[mb][xt], 0, 0, 0);
                            acc[mb][xt] = __builtin_amdgcn_mfma_f32_16x16x32_bf16(al[mb], bh[xt], acc[mb][xt], 0, 0, 0);
                        }
                }
            }
        }
    }
    float* ob = out + (((size_t)(n * 16 + t) * 24) + y) * (24 * 128) + cg * 64;
    #pragma unroll
    for (int mb = 0; mb < 4; ++mb) {
        f32x4 bv = *(const f32x4*)(bias + cg * 64 + mb * 16 + q * 4);
        f32x4 v0 = acc[mb][0] + bv;
        f32x4 v1 = acc[mb][1] + bv;
        *(f32x4*)(ob + c * 128 + mb * 16 + q * 4) = v0;
        if (c < 8) *(f32x4*)(ob + (16 + c) * 128 + mb * 16 + q * 4) = v1;
        #pragma unroll
        for (int r = 0; r < 4; ++r) {
            float s  = v0[r] + (c < 8 ? v1[r] : 0.f);
            float q2 = v0[r] * v0[r] + (c < 8 ? v1[r] * v1[r] : 0.f);
            #pragma unroll
            for (int m = 1; m < 16; m <<= 1) { s += __shfl_xor(s, m, 64); q2 += __shfl_xor(q2, m, 64); }
            if (c == 0) { sred[wv][mb * 16 + q * 4 + r] = s; qred[wv][mb * 16 + q * 4 + r] = q2; }
        }
    }
    __syncthreads();
    if (threadIdx.x < 64) {
        int co = cg * 64 + threadIdx.x;
        float s = sred[0][threadIdx.x] + sred[1][threadIdx.x] + sred[2][threadIdx.x] + sred[3][threadIdx.x];
        float q2 = qred[0][threadIdx.x] + qred[1][threadIdx.x] + qred[2][threadIdx.x] + qred[3][threadIdx.x];
        atomicAdd(&st[co * 2], s);
        atomicAdd(&st[co * 2 + 1], q2);
    }
}

// -------- BN + ReLU + avgpool 6x6 (chan-last in) -> enc ---------------------
__global__ void bnavgk(const float* __restrict__ x, const float* __restrict__ st,
                       const float* __restrict__ gam, const float* __restrict__ bet,
                       float* __restrict__ enc) {
    int i = blockIdx.x * 256 + threadIdx.x;    // 131072
    int c = i & 127; int xo = (i >> 7) & 3; int yo = (i >> 9) & 3;
    int t = (i >> 11) & 15; int n = i >> 15;
    float mean = st[c * 2] * (1.f / 36864.f);
    float var  = st[c * 2 + 1] * (1.f / 36864.f) - mean * mean;
    var = var < 0.f ? 0.f : var;
    float sc = gam[c] / sqrtf(var + 1e-5f);
    float sh = bet[c] - mean * sc;
    const float* base = x + ((((size_t)(n * 16 + t) * 24) + yo * 6) * 24 + xo * 6) * 128 + c;
    float s = 0.f;
    #pragma unroll
    for (int wy = 0; wy < 6; ++wy)
        #pragma unroll
        for (int wx = 0; wx < 6; ++wx)
            s += fmaxf(base[(wy * 24 + wx) * 128] * sc + sh, 0.f);
    enc[(size_t)n * 32768 + (size_t)c * 256 + t * 16 + yo * 4 + xo] = s * (1.f / 36.f);
}

// -------- weight prepack kernels -------------------------------------------
__global__ void prep2k(const float* __restrict__ c2w, unsigned short* __restrict__ w2p) {
    int i = blockIdx.x * 256 + threadIdx.x;    // 110592
    if (i >= 110592) return;
    int ci = i & 31; int co = (i >> 5) & 63; int h = (i >> 11) & 1;
    int o = (i >> 12) % 9; int kt = i / 36864;
    int ky = o / 3, kx = o % 3;
    float w = c2w[(((size_t)(co * 32 + ci) * 3 + kt) * 3 + ky) * 3 + kx];
    unsigned short hi = f2bf(w);
    w2p[i] = h ? f2bf(w - bf2f(hi)) : hi;
}
__global__ void prep3k(const float* __restrict__ c3w, unsigned short* __restrict__ w3p) {
    int i = blockIdx.x * 256 + threadIdx.x;    // 442368
    if (i >= 442368) return;
    int cil = i & 31; int cop = (i >> 5) & 63; int kc = (i >> 11) & 1; int h = (i >> 12) & 1;
    int kx = (i >> 13) % 3; int ky = (i / 24576) % 3; int kt = (i / 73728) % 3; int cg = i / 221184;
    int ci = kc * 32 + cil; int co = cg * 64 + cop;
    float w = c3w[(((size_t)(co * 64 + ci) * 3 + kt) * 3 + ky) * 3 + kx];
    unsigned short hi = f2bf(w);
    w3p[i] = h ? f2bf(w - bf2f(hi)) : hi;
}
__global__ void prepwhhk(const float* __restrict__ whh, float* __restrict__ wt) {
    int i = blockIdx.x * 256 + threadIdx.x;    // 196608
    int g = i % 768, k = i / 768;
    wt[i] = whh[(size_t)g * 256 + k];
}

// -------- codebook transpose: cb[8192][256] -> cbT[256][8192] ---------------
__global__ void transck(const float* __restrict__ cb, float* __restrict__ cbT) {
    __shared__ float t[32][33];
    int bx = blockIdx.x & 255;
    int by = blockIdx.x >> 8;
    int ld = threadIdx.x & 31, lk = threadIdx.x >> 5;
    #pragma unroll
    for (int i = 0; i < 4; ++i) {
        int kl = lk + i * 8;
        t[kl][ld] = cb[(size_t)(bx * 32 + kl) * 256 + by * 32 + ld];
    }
    __syncthreads();
    #pragma unroll
    for (int i = 0; i < 4; ++i) {
        int dl = lk + i * 8;
        cbT[(size_t)(by * 32 + dl) * 8192 + bx * 32 + ld] = t[ld][dl];
    }
}

// -------- code norms in fp64 (ascending d, matches reference order) ---------
__global__ void cnormk(const float* __restrict__ cbT, double* __restrict__ cn2) {
    int k = blockIdx.x * 256 + threadIdx.x;    // 8192
    double s = 0.0;
    for (int d = 0; d < 256; ++d) {
        double c = (double)cbT[(size_t)d * 8192 + k];
        s += c * c;
    }
    cn2[k] = s;
}

// -------- proj init: feat = pb broadcast ------------------------------------
__global__ void projinitk(const float* __restrict__ pb, float* __restrict__ feat) {
    int i = blockIdx.x * 256 + threadIdx.x;    // 7168
    feat[i] = pb[i & 255];
}

// -------- proj (K-split x8): feat[r][d] += enc[r-chunk] . pw[d-chunk] -------
__global__ void projk(const float* __restrict__ enc, const float* __restrict__ pw,
                      float* __restrict__ feat) {
    int d = blockIdx.x & 255; int ch = blockIdx.x >> 8;    // 2048 blocks
    int k0 = ch * 4096;
    float acc[28];
    #pragma unroll
    for (int e = 0; e < 28; ++e) acc[e] = 0.f;
    const float* wrow = pw + (size_t)d * 32768 + k0;
    for (int k = threadIdx.x; k < 4096; k += 256) {
        float wv = wrow[k];
        #pragma unroll
        for (int e = 0; e < 28; ++e) acc[e] += enc[(size_t)e * 32768 + k0 + k] * wv;
    }
    __shared__ float red[4 * 28];
    #pragma unroll
    for (int e = 0; e < 28; ++e) {
        float v = acc[e];
        #pragma unroll
        for (int o = 32; o > 0; o >>= 1) v += __shfl_down(v, o, 64);
        if ((threadIdx.x & 63) == 0) red[(threadIdx.x >> 6) * 28 + e] = v;
    }
    __syncthreads();
    if (threadIdx.x < 28) {
        int e = threadIdx.x;
        int l = e >> 2, n = e & 3;
        float s = red[e] + red[28 + e] + red[56 + e] + red[84 + e];
        atomicAdd(&feat[(size_t)(n * 7 + l) * 256 + d], s);
    }
}

// -------- VQ: argmin over transposed codebook, fp64, 896 blocks -------------
__global__ void quantk(const float* __restrict__ feat, const float* __restrict__ cbT,
                       const double* __restrict__ cn2, unsigned long long* __restrict__ best) {
    int kc = blockIdx.x & 31, r = blockIdx.x >> 5;     // 896 = 32kc * 28r
    int k = kc * 256 + threadIdx.x;
    __shared__ float fs[256];
    fs[threadIdx.x] = feat[(size_t)r * 256 + threadIdx.x];
    __syncthreads();
    double dot = 0.0;
    for (int d = 0; d < 256; ++d)
        dot += (double)cbT[(size_t)d * 8192 + k] * (double)fs[d];
    float s = (float)(cn2[k] - 2.0 * dot);
    unsigned int bits = __float_as_uint(s);
    unsigned int key = (bits & 0x80000000u) ? ~bits : (bits | 0x80000000u);
    unsigned long long p = ((unsigned long long)key << 32) | (unsigned int)k;
    #pragma unroll
    for (int o = 32; o > 0; o >>= 1) {
        unsigned long long qv = __shfl_down(p, o, 64);
        if (qv < p) p = qv;
    }
    if ((threadIdx.x & 63) == 0) atomicMin(&best[r], p);
}

__global__ void gatherk(const unsigned long long* __restrict__ best,
                        const float* __restrict__ feat, const float* __restrict__ cb,
                        float* __restrict__ dout, float* __restrict__ quant,
                        float* __restrict__ acc) {
    int r = blockIdx.x;
    int d = threadIdx.x;
    int idx = (int)(best[r] & 0xFFFFFFFFull);
    float q = cb[(size_t)idx * 256 + d];
    quant[r * 256 + d] = q;
    dout[28 + r * 256 + d] = q;
    if (d == 0) dout[r] = (float)idx;
    float df = feat[r * 256 + d] - q;
    float v = df * df;
    #pragma unroll
    for (int o = 32; o > 0; o >>= 1) v += __shfl_down(v, o, 64);
    if ((d & 63) == 0) atomicAdd(&acc[0], v);
}

__global__ void gxk(const float* __restrict__ quant, const float* __restrict__ wih,
                    const float* __restrict__ bih, float* __restrict__ gx) {
    int o = blockIdx.x * 256 + threadIdx.x;
    int g = o % 768; int t = (o / 768) % 6; int n = o / (768 * 6);
    const float* q = quant + (size_t)(n * 7 + t) * 256;
    const float* w = wih + (size_t)g * 256;
    float s = bih[g];
    #pragma unroll 4
    for (int d = 0; d < 256; ++d) s += q[d] * w[d];
    gx[o] = s;
}

// -------- all 6 GRU steps in one kernel (block = batch b) -------------------
__global__ void gru_allk(const float* __restrict__ gx, const float* __restrict__ wt,
                         const float* __restrict__ bhh, const float* __restrict__ feat,
                         float* __restrict__ acc) {
    int b = blockIdx.x;        // 4
    int d = threadIdx.x;       // 256
    __shared__ float hs[256];
    hs[d] = 0.f;
    __syncthreads();
    float ctx = 0.f;
    for (int t = 0; t < 6; ++t) {
        float g0 = bhh[d], g1 = bhh[256 + d], g2 = bhh[512 + d];
        #pragma unroll 4
        for (int k = 0; k < 256; ++k) {
            float hv = hs[k];
            const float* wr = wt + (size_t)k * 768;
            g0 += wr[d] * hv; g1 += wr[256 + d] * hv; g2 += wr[512 + d] * hv;
        }
        const float* gxr = gx + (size_t)(b * 6 + t) * 768;
        float xr = gxr[d], xz = gxr[256 + d], xn = gxr[512 + d];
        float rr = 1.f / (1.f + expf(-(xr + g0)));
        float zz = 1.f / (1.f + expf(-(xz + g1)));
        float nn = tanhf(xn + rr * g2);
        float h2 = (1.f - zz) * nn + zz * hs[d];
        __syncthreads();
        hs[d] = h2;
        __syncthreads();
        float df = h2 - feat[(size_t)(b * 7 + t + 1) * 256 + d];
        ctx += df * df;
    }
    #pragma unroll
    for (int o = 32; o > 0; o >>= 1) ctx += __shfl_down(ctx, o, 64);
    if ((d & 63) == 0) atomicAdd(&acc[1], ctx);
}

__global__ void fink(const float* __restrict__ acc, float* __restrict__ dout) {
    float comm = acc[0] / 7168.f;
    float ctx  = acc[1] / 6144.f;
    dout[7196] = comm;
    dout[7197] = comm;
    dout[7198] = ctx;
    dout[7199] = comm + 0.25f * comm + 0.1f * ctx;
}

// ---------------------------------------------------------------------------
extern "C" void kernel_launch(void* const* d_in, const int* in_sizes, int n_in,
                              void* d_out, int out_size, void* d_ws, size_t ws_size,
                              hipStream_t stream) {
    (void)in_sizes; (void)n_in; (void)out_size; (void)ws_size;
    const float* x    = (const float*)d_in[0];
    const float* c1w  = (const float*)d_in[1];
    const float* c1b  = (const float*)d_in[2];
    const float* bn1g = (const float*)d_in[3];
    const float* bn1b = (const float*)d_in[4];
    const float* c2w  = (const float*)d_in[5];
    const float* c2b  = (const float*)d_in[6];
    const float* bn2g = (const float*)d_in[7];
    const float* bn2b = (const float*)d_in[8];
    const float* c3w  = (const float*)d_in[9];
    const float* c3b  = (const float*)d_in[10];
    const float* bn3g = (const float*)d_in[11];
    const float* bn3b = (const float*)d_in[12];
    const float* pw   = (const float*)d_in[13];
    const float* pb   = (const float*)d_in[14];
    const float* cb   = (const float*)d_in[15];
    const float* wih  = (const float*)d_in[16];
    const float* whh  = (const float*)d_in[17];
    const float* bih  = (const float*)d_in[18];
    const float* bhh  = (const float*)d_in[19];
    float* out = (float*)d_out;

    // ---- workspace layout (bytes) ----
    char* w = (char*)d_ws;
    float* A  = (float*)w;                         w += 75497472;   // conv2/3 outs; pmax/pmin + cbT alias
    float* PMAX = A;                                                // 18.87 MB (alias)
    float* PMIN = A + 4718592;                                      // 18.87 MB (alias)
    float* cbT = A;                                                 // 8 MB (alias, post-loop)
    double* cn2 = (double*)((char*)A + 8388608);                    // 64 KB (alias, post-loop)
    char*  SH = w;                                 w += 16293888;   // P3 hi/lo
    unsigned short* P3h = (unsigned short*)SH;
    unsigned short* P3l = (unsigned short*)(SH + 8146944);
    unsigned short* P2h = (unsigned short*)w;      w += 11980800;
    unsigned short* P2l = (unsigned short*)w;      w += 11980800;
    unsigned short* W2P = (unsigned short*)w;      w += 221184;
    unsigned short* W3P = (unsigned short*)w;      w += 884736;
    float* WT    = (float*)w;                      w += 786432;     // whh transposed [256][768]
    float* enc   = (float*)w;                      w += 3670016;
    float* feat  = (float*)w;                      w += 28672;
    float* quant = (float*)w;                      w += 28672;
    float* gx    = (float*)w;                      w += 73728;
    float* statsA = (float*)w;                     w += 21504;      // 21 x 256 floats
    float* acc    = (float*)w;                     w += 16;
    unsigned long long* best = (unsigned long long*)w;  w += 224;

    // ---- per-launch init ----
    hipMemsetAsync(P2h, 0, 11980800 * 2, stream);                  // P2 hi+lo pads
    hipMemsetAsync(statsA, 0, 21504 + 16, stream);                 // stats + acc
    hipMemsetAsync(best, 0xFF, 224, stream);
    prep2k<<<432, 256, 0, stream>>>(c2w, W2P);
    prep3k<<<1728, 256, 0, stream>>>(c3w, W3P);
    prepwhhk<<<768, 256, 0, stream>>>(whh, WT);

    for (int l = 0; l < 7; ++l) {
        float* st1 = statsA + (l * 3 + 0) * 256;
        float* st2 = statsA + (l * 3 + 1) * 256;
        float* st3 = statsA + (l * 3 + 2) * 256;
        conv1k<<<768, 256, 0, stream>>>(x, c1w, c1b, PMAX, PMIN, st1, l * 8);
        bnpool1b<<<2304, 256, 0, stream>>>(PMAX, PMIN, st1, bn1g, bn1b, P2h, P2l);
        conv2k<<<768, 256, 0, stream>>>(P2h, P2l, W2P, c2b, A, st2);
        bnpool2k<<<1989, 256, 0, stream>>>(A, st2, bn2g, bn2b, P3h, P3l);
        conv3k<<<768, 256, 0, stream>>>(P3h, P3l, W3P, c3b, A, st3);
        bnavgk<<<512, 256, 0, stream>>>(A, st3, bn3g, bn3b, enc + (size_t)l * 131072);
    }

    // A is free now: build transposed codebook + norms in its space
    transck<<<2048, 256, 0, stream>>>(cb, cbT);
    cnormk<<<32, 256, 0, stream>>>(cbT, cn2);
    projinitk<<<28, 256, 0, stream>>>(pb, feat);
    projk<<<2048, 256, 0, stream>>>(enc, pw, feat);
    quantk<<<896, 256, 0, stream>>>(feat, cbT, cn2, best);
    gatherk<<<28, 256, 0, stream>>>(best, feat, cb, out, quant, acc);
    gxk<<<72, 256, 0, stream>>>(quant, wih, bih, gx);
    gru_allk<<<4, 256, 0, stream>>>(gx, WT, bhh, feat, acc);
    fink<<<1, 1, 0, stream>>>(acc, out);
}